// Round 1
// baseline (2436.422 us; speedup 1.0000x reference)
//
#include <hip/hip_runtime.h>
#include <math.h>

// WaveNet residual block, fused single kernel, fp32 vector (no fp32 MFMA on CDNA4).
// B=32, C=128, T=16000, K=2, dilation=2 (hardcoded; setup_inputs fixes dil=2).
//
// Per block: batch b, time tile of TT=63 output columns [ts, ts+62].
//   phase 0: stage x[b, :, ts-3 .. ts+62] (66 cols) into LDS (zero-padded at edges)
//   phase 1: o[ch][j] = tanh(f)*sigmoid(g) for o-cols j=0..63 <-> abs time u = ts-1+j
//            f/g[co][u] = sum_ci wf[co,ci,0]*x[ci,u-2] + wf[co,ci,1]*x[ci,u]
//   phase 2: skip[co][t] = sum_ci ws[co,ci,0]*o[ci,t-1] + ws[co,ci,1]*o[ci,t]
//            out = skip + x;  store out cols jj=0..62 (t = ts+jj < T)
//
// Thread layout (256 thr = 4 waves): tg = tid&15 -> 4 consecutive cols, cg = tid>>4
// -> 8 consecutive out-channels. Register tile 8co x 4t, two accumulator sets (f,g).

#define CCH 128
#define TLEN 16000
#define NB 32
#define TT 63        // output cols per block
#define XH 66        // x halo cols: [ts-3, ts+62]
#define XSTRIDE 68   // padded so every row is 16B-aligned for float4 LDS reads
#define OSTRIDE 68

__global__ __launch_bounds__(256, 2)
void wavenet_fused_f32(const float* __restrict__ x,
                       const float* __restrict__ wf,
                       const float* __restrict__ wg,
                       const float* __restrict__ wsk,
                       float* __restrict__ out,
                       float* __restrict__ skip)
{
    __shared__ float xs[CCH][XSTRIDE];  // x tile, col c <-> abs time ts-3+c
    __shared__ float os[CCH][OSTRIDE];  // o tile, col j <-> abs time ts-1+j (64 cols used)

    const int b  = blockIdx.y;
    const int ts = blockIdx.x * TT;
    const int tid = threadIdx.x;

    // ---------------- phase 0: stage x tile ----------------
    const float* xb = x + (size_t)b * CCH * TLEN;
    for (int i = tid; i < CCH * XH; i += 256) {
        const int ch = i / XH, col = i % XH;
        const int t = ts - 3 + col;
        float v = 0.f;
        if (t >= 0 && t < TLEN) v = xb[ch * TLEN + t];
        xs[ch][col] = v;
    }
    __syncthreads();

    const int tg  = tid & 15;
    const int cg  = tid >> 4;
    const int tl  = tg * 4;     // local col base (0..60)
    const int co0 = cg * 8;

    // ---------------- phase 1: f/g GEMM + gated activation ----------------
    float ff[8][4], gg[8][4];
    #pragma unroll
    for (int c = 0; c < 8; ++c)
        #pragma unroll
        for (int j = 0; j < 4; ++j) { ff[c][j] = 0.f; gg[c][j] = 0.f; }

    for (int ci = 0; ci < CCH; ci += 2) {
        // o-col j taps: tap0 = xs[ci][j] (x[u-2]), tap1 = xs[ci][j+2] (x[u])
        const float4 a0 = *(const float4*)&xs[ci][tl];
        const float4 a1 = *(const float4*)&xs[ci][tl + 4];
        const float4 b0 = *(const float4*)&xs[ci + 1][tl];
        const float4 b1 = *(const float4*)&xs[ci + 1][tl + 4];
        const float t0a[4] = {a0.x, a0.y, a0.z, a0.w};
        const float t1a[4] = {a0.z, a0.w, a1.x, a1.y};
        const float t0b[4] = {b0.x, b0.y, b0.z, b0.w};
        const float t1b[4] = {b0.z, b0.w, b1.x, b1.y};
        #pragma unroll
        for (int c = 0; c < 8; ++c) {
            // w[co][ci][k] flat: (co*C + ci)*2 + k ; float4 covers (ci,k0..ci+1,k1), 16B-aligned (ci even)
            const float4 w4f = *(const float4*)&wf[((size_t)(co0 + c) * CCH + ci) * 2];
            const float4 w4g = *(const float4*)&wg[((size_t)(co0 + c) * CCH + ci) * 2];
            #pragma unroll
            for (int j = 0; j < 4; ++j) {
                ff[c][j] = fmaf(w4f.x, t0a[j], ff[c][j]);
                ff[c][j] = fmaf(w4f.y, t1a[j], ff[c][j]);
                ff[c][j] = fmaf(w4f.z, t0b[j], ff[c][j]);
                ff[c][j] = fmaf(w4f.w, t1b[j], ff[c][j]);
                gg[c][j] = fmaf(w4g.x, t0a[j], gg[c][j]);
                gg[c][j] = fmaf(w4g.y, t1a[j], gg[c][j]);
                gg[c][j] = fmaf(w4g.z, t0b[j], gg[c][j]);
                gg[c][j] = fmaf(w4g.w, t1b[j], gg[c][j]);
            }
        }
    }

    #pragma unroll
    for (int c = 0; c < 8; ++c) {
        float4 ov;
        float* po = (float*)&ov;
        #pragma unroll
        for (int j = 0; j < 4; ++j) {
            const float f = ff[c][j], g = gg[c][j];
            const float e2 = __expf(-2.f * f);
            const float th = (1.f - e2) / (1.f + e2);   // tanh(f)
            const float sg = 1.f / (1.f + __expf(-g));  // sigmoid(g)
            po[j] = th * sg;
        }
        *(float4*)&os[co0 + c][tl] = ov;
    }
    __syncthreads();

    // ---------------- phase 2: skip GEMM + residual ----------------
    float sk[8][4];
    #pragma unroll
    for (int c = 0; c < 8; ++c)
        #pragma unroll
        for (int j = 0; j < 4; ++j) sk[c][j] = 0.f;

    for (int ci = 0; ci < CCH; ci += 2) {
        // out col jj = tl+j, t = ts+jj: tap0 = o[t-1] -> os col jj ; tap1 = o[t] -> os col jj+1
        const float4 a0 = *(const float4*)&os[ci][tl];
        const float4 a1 = *(const float4*)&os[ci][tl + 4];
        const float4 b0 = *(const float4*)&os[ci + 1][tl];
        const float4 b1 = *(const float4*)&os[ci + 1][tl + 4];
        const float t0a[4] = {a0.x, a0.y, a0.z, a0.w};
        const float t1a[4] = {a0.y, a0.z, a0.w, a1.x};
        const float t0b[4] = {b0.x, b0.y, b0.z, b0.w};
        const float t1b[4] = {b0.y, b0.z, b0.w, b1.x};
        #pragma unroll
        for (int c = 0; c < 8; ++c) {
            const float4 w4s = *(const float4*)&wsk[((size_t)(co0 + c) * CCH + ci) * 2];
            #pragma unroll
            for (int j = 0; j < 4; ++j) {
                sk[c][j] = fmaf(w4s.x, t0a[j], sk[c][j]);
                sk[c][j] = fmaf(w4s.y, t1a[j], sk[c][j]);
                sk[c][j] = fmaf(w4s.z, t0b[j], sk[c][j]);
                sk[c][j] = fmaf(w4s.w, t1b[j], sk[c][j]);
            }
        }
    }

    float* outb = out  + (size_t)b * CCH * TLEN;
    float* skb  = skip + (size_t)b * CCH * TLEN;
    #pragma unroll
    for (int c = 0; c < 8; ++c) {
        #pragma unroll
        for (int j = 0; j < 4; ++j) {
            const int jj = tl + j;
            const int t  = ts + jj;
            if (jj < TT && t < TLEN) {
                const float s = sk[c][j];
                outb[(size_t)(co0 + c) * TLEN + t] = s + xs[co0 + c][jj + 3];  // residual: x[t] at xs col jj+3
                skb [(size_t)(co0 + c) * TLEN + t] = s;
            }
        }
    }
}

extern "C" void kernel_launch(void* const* d_in, const int* in_sizes, int n_in,
                              void* d_out, int out_size, void* d_ws, size_t ws_size,
                              hipStream_t stream) {
    const float* x   = (const float*)d_in[0];
    const float* wf  = (const float*)d_in[1];
    const float* wg  = (const float*)d_in[2];
    const float* wsk = (const float*)d_in[3];
    // d_in[4] = dilation (=2, hardcoded in the kernel's halo indexing)

    float* out  = (float*)d_out;
    float* skip = out + (size_t)NB * CCH * TLEN;  // tuple (out, skip) concatenated flat

    dim3 grid((TLEN + TT - 1) / TT, NB);  // 254 x 32
    wavenet_fused_f32<<<grid, 256, 0, stream>>>(x, wf, wg, wsk, out, skip);
}